// Round 4
// baseline (458.102 us; speedup 1.0000x reference)
//
#include <hip/hip_runtime.h>
#include <stdint.h>

#define B_      32
#define T_      1024
#define D_      512
#define MAXLEN_ 8192

// clang-native float4: __builtin_nontemporal_store accepts vectors of float,
// but NOT HIP's float4 (a HIP_vector_type class). Same 16B layout.
typedef float f4 __attribute__((ext_vector_type(4)));

// ---------------------------------------------------------------------------
// Kernel 1: per-batch inclusive cumsum of duration (int32 in, int32 out) +
// mel_len written (as float) into the tail of d_out.
// One block of T_ threads per batch; Hillis-Steele scan in LDS.
// ---------------------------------------------------------------------------
__global__ void lr_cumsum_kernel(const int* __restrict__ dur,
                                 int* __restrict__ cum,
                                 float* __restrict__ mel_out) {
    int b = blockIdx.x;
    int t = threadIdx.x;
    __shared__ int s[T_];
    s[t] = dur[b * T_ + t];
    __syncthreads();
    #pragma unroll
    for (int off = 1; off < T_; off <<= 1) {
        int v = (t >= off) ? s[t - off] : 0;
        __syncthreads();
        s[t] += v;
        __syncthreads();
    }
    cum[b * T_ + t] = s[t];
    if (t == T_ - 1) {
        mel_out[b] = (float)s[t];
    }
}

// ---------------------------------------------------------------------------
// Kernel 2: idx[b,p] = searchsorted(cum[b,:], p, side='right'), or -1 if
// p >= mel_len[b] (masked -> output row is zero).
// ---------------------------------------------------------------------------
__global__ void lr_idx_kernel(const int* __restrict__ cum,
                              int* __restrict__ idx) {
    int gid = blockIdx.x * blockDim.x + threadIdx.x;
    if (gid >= B_ * MAXLEN_) return;
    int b = gid >> 13;               // MAXLEN_ = 8192 = 2^13
    int p = gid & (MAXLEN_ - 1);
    const int* c = cum + b * T_;
    int mel = c[T_ - 1];
    int r;
    if (p >= mel) {
        r = -1;
    } else {
        // first t with c[t] > p  (searchsorted side='right')
        int lo = 0, hi = T_;
        #pragma unroll
        for (int it = 0; it < 10; ++it) {   // log2(1024) = 10 fixed steps
            int mid = (lo + hi) >> 1;
            if (c[mid] <= p) lo = mid + 1; else hi = mid;
        }
        r = lo;                              // in [0, T_-1] since p < c[T_-1]
    }
    idx[gid] = r;
}

// ---------------------------------------------------------------------------
// Kernel 3: gather rows. 2 float4 (32B) per lane per iter, coalesced.
// Non-temporal stores: the 512 MiB output stream must not evict x (64 MiB,
// re-read ~3.5x) from L2.  out[b, p, :] = (idx >= 0) ? x[b, idx, :] : 0
// ---------------------------------------------------------------------------
__global__ void lr_gather_kernel(const f4* __restrict__ x,
                                 const int* __restrict__ idx,
                                 f4* __restrict__ out) {
    const long long total  = (long long)B_ * MAXLEN_ * (D_ / 4);   // 33.5M f4
    const long long stride = 2LL * gridDim.x * blockDim.x;
    for (long long g0 = 2LL * ((long long)blockIdx.x * blockDim.x + threadIdx.x);
         g0 < total; g0 += stride) {
        #pragma unroll
        for (int u = 0; u < 2; ++u) {
            long long gid = g0 + u;
            int row = (int)(gid >> 7);           // D_/4 = 128 float4 per row
            int c   = (int)(gid & 127);
            int t   = idx[row];
            f4 v = (f4){0.f, 0.f, 0.f, 0.f};
            if (t >= 0) {
                int b = row >> 13;
                v = x[(((long long)(b * T_ + t)) << 7) | c];
            }
            __builtin_nontemporal_store(v, &out[gid]);
        }
    }
}

// ---------------------------------------------------------------------------
// Fallback (ws too small for the idx array): fused binary search per lane.
// ---------------------------------------------------------------------------
__global__ void lr_gather_fused_kernel(const f4* __restrict__ x,
                                       const int* __restrict__ cum,
                                       f4* __restrict__ out) {
    const long long total = (long long)B_ * MAXLEN_ * (D_ / 4);
    const long long stride = (long long)gridDim.x * blockDim.x;
    for (long long gid = (long long)blockIdx.x * blockDim.x + threadIdx.x;
         gid < total; gid += stride) {
        int row = (int)(gid >> 7);
        int c   = (int)(gid & 127);
        int b   = row >> 13;
        int p   = row & (MAXLEN_ - 1);
        const int* cm = cum + b * T_;
        int mel = cm[T_ - 1];
        f4 v = (f4){0.f, 0.f, 0.f, 0.f};
        if (p < mel) {
            int lo = 0, hi = T_;
            #pragma unroll
            for (int it = 0; it < 10; ++it) {
                int mid = (lo + hi) >> 1;
                if (cm[mid] <= p) lo = mid + 1; else hi = mid;
            }
            v = x[(((long long)(b * T_ + lo)) << 7) | c];
        }
        __builtin_nontemporal_store(v, &out[gid]);
    }
}

extern "C" void kernel_launch(void* const* d_in, const int* in_sizes, int n_in,
                              void* d_out, int out_size, void* d_ws, size_t ws_size,
                              hipStream_t stream) {
    const float* x   = (const float*)d_in[0];
    const int*   dur = (const int*)d_in[1];   // harness converts integers to int32
    // d_in[2] = max_len scalar (8192) — compile-time constant here.

    float* out     = (float*)d_out;
    float* mel_out = out + (size_t)B_ * MAXLEN_ * D_;   // output 1 tail

    int* cum = (int*)d_ws;                               // B_*T_ int32 = 128 KB
    const size_t need_cum  = (size_t)B_ * T_ * sizeof(int);
    const size_t need_full = need_cum + (size_t)B_ * MAXLEN_ * sizeof(int);

    lr_cumsum_kernel<<<B_, T_, 0, stream>>>(dur, cum, mel_out);

    if (ws_size >= need_full) {
        int* idx = cum + B_ * T_;                        // B_*MAXLEN_ int32 = 1 MB
        lr_idx_kernel<<<(B_ * MAXLEN_) / 256, 256, 0, stream>>>(cum, idx);
        lr_gather_kernel<<<4096, 256, 0, stream>>>((const f4*)x, idx,
                                                   (f4*)out);
    } else {
        lr_gather_fused_kernel<<<4096, 256, 0, stream>>>((const f4*)x, cum,
                                                         (f4*)out);
    }
}

// Round 5
// 133.719 us; speedup vs baseline: 3.4259x; 3.4259x over previous
//
#include <hip/hip_runtime.h>
#include <stdint.h>

#define B_      32
#define T_      1024
#define D_      512
#define MAXLEN_ 8192

typedef float f4 __attribute__((ext_vector_type(4)));

// ---------------------------------------------------------------------------
// Kernel 1 (fused): per-batch inclusive scan of duration in LDS, mel_len to
// the tail of d_out, and searchsorted(cum, p, 'right') for all 8192 positions
// of this batch (8 per thread, stride-1024 coalesced writes). cum never
// touches global memory.
// ---------------------------------------------------------------------------
__global__ void lr_scan_idx_kernel(const int* __restrict__ dur,
                                   int* __restrict__ idx,
                                   float* __restrict__ mel_out) {
    int b = blockIdx.x;
    int t = threadIdx.x;
    __shared__ int s[T_];
    s[t] = dur[b * T_ + t];
    __syncthreads();
    #pragma unroll
    for (int off = 1; off < T_; off <<= 1) {
        int v = (t >= off) ? s[t - off] : 0;
        __syncthreads();
        s[t] += v;
        __syncthreads();
    }
    int mel = s[T_ - 1];
    if (t == T_ - 1) {
        mel_out[b] = (float)mel;
    }
    #pragma unroll
    for (int k = 0; k < MAXLEN_ / T_; ++k) {      // 8 positions per thread
        int p = t + k * T_;
        int r = -1;
        if (p < mel) {
            int lo = 0, hi = T_;
            #pragma unroll
            for (int it = 0; it < 10; ++it) {     // log2(1024) fixed steps
                int mid = (lo + hi) >> 1;
                if (s[mid] <= p) lo = mid + 1; else hi = mid;
            }
            r = lo;                               // first t with cum[t] > p
        }
        idx[b * MAXLEN_ + p] = r;
    }
}

// ---------------------------------------------------------------------------
// Kernel 2: gather rows. Exact grid (no grid-stride): each lane owns 2
// consecutive float4 (32B); a wave covers 2KB contiguous output. Regular
// (cached) stores -- L2 write-combining is required for full-line HBM writes
// (nt 16B stores measured 2x write amplification on gfx950).
// out[b, p, :] = (idx >= 0) ? x[b, idx, :] : 0
// ---------------------------------------------------------------------------
__global__ __launch_bounds__(256) void lr_gather_kernel(
        const f4* __restrict__ x,
        const int* __restrict__ idx,
        f4* __restrict__ out) {
    long long gid0 = ((long long)blockIdx.x * blockDim.x + threadIdx.x) * 2;
    int row = (int)(gid0 >> 7);                  // 128 float4 per output row
    int c   = (int)(gid0 & 127);                 // even; c+1 in same row
    int t   = idx[row];
    if (t >= 0) {
        int b = row >> 13;                       // MAXLEN_ = 2^13
        const f4* src = x + ((((long long)(b * T_ + t)) << 7) | c);
        out[gid0]     = src[0];
        out[gid0 + 1] = src[1];
    } else {
        f4 z = (f4){0.f, 0.f, 0.f, 0.f};
        out[gid0]     = z;
        out[gid0 + 1] = z;
    }
}

// ---------------------------------------------------------------------------
// Fallback (ws too small for the 1MB idx array): cum in ws + fused search.
// ---------------------------------------------------------------------------
__global__ void lr_cumsum_kernel(const int* __restrict__ dur,
                                 int* __restrict__ cum,
                                 float* __restrict__ mel_out) {
    int b = blockIdx.x;
    int t = threadIdx.x;
    __shared__ int s[T_];
    s[t] = dur[b * T_ + t];
    __syncthreads();
    #pragma unroll
    for (int off = 1; off < T_; off <<= 1) {
        int v = (t >= off) ? s[t - off] : 0;
        __syncthreads();
        s[t] += v;
        __syncthreads();
    }
    cum[b * T_ + t] = s[t];
    if (t == T_ - 1) mel_out[b] = (float)s[t];
}

__global__ void lr_gather_fused_kernel(const f4* __restrict__ x,
                                       const int* __restrict__ cum,
                                       f4* __restrict__ out) {
    const long long total = (long long)B_ * MAXLEN_ * (D_ / 4);
    const long long stride = (long long)gridDim.x * blockDim.x;
    for (long long gid = (long long)blockIdx.x * blockDim.x + threadIdx.x;
         gid < total; gid += stride) {
        int row = (int)(gid >> 7);
        int c   = (int)(gid & 127);
        int b   = row >> 13;
        int p   = row & (MAXLEN_ - 1);
        const int* cm = cum + b * T_;
        int mel = cm[T_ - 1];
        f4 v = (f4){0.f, 0.f, 0.f, 0.f};
        if (p < mel) {
            int lo = 0, hi = T_;
            #pragma unroll
            for (int it = 0; it < 10; ++it) {
                int mid = (lo + hi) >> 1;
                if (cm[mid] <= p) lo = mid + 1; else hi = mid;
            }
            v = x[(((long long)(b * T_ + lo)) << 7) | c];
        }
        out[gid] = v;
    }
}

extern "C" void kernel_launch(void* const* d_in, const int* in_sizes, int n_in,
                              void* d_out, int out_size, void* d_ws, size_t ws_size,
                              hipStream_t stream) {
    const float* x   = (const float*)d_in[0];
    const int*   dur = (const int*)d_in[1];   // harness converts integers to int32
    // d_in[2] = max_len scalar (8192) -- compile-time constant here.

    float* out     = (float*)d_out;
    float* mel_out = out + (size_t)B_ * MAXLEN_ * D_;   // output 1 tail

    const size_t need_idx = (size_t)B_ * MAXLEN_ * sizeof(int);   // 1 MB

    if (ws_size >= need_idx) {
        int* idx = (int*)d_ws;
        lr_scan_idx_kernel<<<B_, T_, 0, stream>>>(dur, idx, mel_out);
        // 33,554,432 float4 / (256 threads * 2 f4) = 65536 blocks, exact cover
        lr_gather_kernel<<<(B_ * MAXLEN_ * (D_ / 4)) / (256 * 2), 256, 0, stream>>>(
            (const f4*)x, idx, (f4*)out);
    } else {
        int* cum = (int*)d_ws;                            // 128 KB
        lr_cumsum_kernel<<<B_, T_, 0, stream>>>(dur, cum, mel_out);
        lr_gather_fused_kernel<<<4096, 256, 0, stream>>>((const f4*)x, cum,
                                                         (f4*)out);
    }
}

// Round 6
// 118.818 us; speedup vs baseline: 3.8555x; 1.1254x over previous
//
#include <hip/hip_runtime.h>
#include <stdint.h>

#define B_      32
#define T_      1024
#define D_      512
#define MAXLEN_ 8192

typedef float f4 __attribute__((ext_vector_type(4)));

// ---------------------------------------------------------------------------
// Kernel 1: per-batch shuffle-based inclusive scan (1 barrier) + DIRECT
// scatter of the expansion index (no binary search): thread t owns output
// positions [cum_prev, cum) and writes t there; tail [mel, 8192) gets -1
// (disjoint ranges -> no second barrier). mel_len -> tail of d_out.
// ---------------------------------------------------------------------------
__global__ void lr_scan_scatter_kernel(const int* __restrict__ dur,
                                       int* __restrict__ idx,
                                       float* __restrict__ mel_out) {
    int b    = blockIdx.x;
    int t    = threadIdx.x;        // 0..1023
    int lane = t & 63;
    int wave = t >> 6;             // 0..15

    int d = dur[b * T_ + t];

    // wave-level inclusive scan (no barriers)
    int v = d;
    #pragma unroll
    for (int off = 1; off < 64; off <<= 1) {
        int n = __shfl_up(v, off, 64);
        if (lane >= off) v += n;
    }

    __shared__ int wsum[16];
    if (lane == 63) wsum[wave] = v;
    __syncthreads();

    int off = 0, tot = 0;
    #pragma unroll
    for (int w = 0; w < 16; ++w) {
        int s = wsum[w];
        off += (w < wave) ? s : 0;
        tot += s;
    }
    int cum  = v + off;            // inclusive cumsum at position t
    int cump = cum - d;            // exclusive

    if (t == T_ - 1) mel_out[b] = (float)tot;

    int* row = idx + b * MAXLEN_;
    for (int j = cump; j < cum; ++j) row[j] = t;          // d in [0,8)
    for (int p = tot + t; p < MAXLEN_; p += T_) row[p] = -1;  // masked tail
}

// ---------------------------------------------------------------------------
// Kernel 2: gather. 8 output rows per 256-thread block (half-wave per row,
// 4 f4 = 64B per lane, each store instruction = 512B-contiguous per
// half-wave). XCD-chunked block swizzle: each XCD owns a contiguous 1/8 of
// the output rows so x-row duplicates (~3.5 adjacent output rows) hit that
// XCD's L2 instead of re-reading L3/HBM.
// out[b, p, :] = (idx >= 0) ? x[b, idx, :] : 0
// ---------------------------------------------------------------------------
__global__ __launch_bounds__(256) void lr_gather_kernel(
        const f4* __restrict__ x,
        const int* __restrict__ idx,
        f4* __restrict__ out) {
    unsigned bid   = blockIdx.x;
    unsigned chunk = gridDim.x >> 3;                 // 32768/8 = 4096
    unsigned nb    = (bid & 7) * chunk + (bid >> 3); // XCD-chunked swizzle

    int row  = (int)(nb * 8) + (int)(threadIdx.x >> 5);  // 8 rows/block
    int colf = (int)(threadIdx.x & 31);                  // f4 col base
    int tt   = idx[row];

    f4* o = out + (((long long)row) << 7) + colf;        // 128 f4 per row
    if (tt >= 0) {
        int b = row >> 13;                               // MAXLEN_ = 2^13
        const f4* src = x + (((long long)(b * T_ + tt)) << 7) + colf;
        o[0]  = src[0];
        o[32] = src[32];
        o[64] = src[64];
        o[96] = src[96];
    } else {
        f4 z = (f4){0.f, 0.f, 0.f, 0.f};
        o[0]  = z;
        o[32] = z;
        o[64] = z;
        o[96] = z;
    }
}

// ---------------------------------------------------------------------------
// Fallback (ws too small for the 1MB idx array): cum in ws + fused search.
// ---------------------------------------------------------------------------
__global__ void lr_cumsum_kernel(const int* __restrict__ dur,
                                 int* __restrict__ cum,
                                 float* __restrict__ mel_out) {
    int b = blockIdx.x;
    int t = threadIdx.x;
    __shared__ int s[T_];
    s[t] = dur[b * T_ + t];
    __syncthreads();
    #pragma unroll
    for (int off = 1; off < T_; off <<= 1) {
        int v = (t >= off) ? s[t - off] : 0;
        __syncthreads();
        s[t] += v;
        __syncthreads();
    }
    cum[b * T_ + t] = s[t];
    if (t == T_ - 1) mel_out[b] = (float)s[t];
}

__global__ void lr_gather_fused_kernel(const f4* __restrict__ x,
                                       const int* __restrict__ cum,
                                       f4* __restrict__ out) {
    const long long total = (long long)B_ * MAXLEN_ * (D_ / 4);
    const long long stride = (long long)gridDim.x * blockDim.x;
    for (long long gid = (long long)blockIdx.x * blockDim.x + threadIdx.x;
         gid < total; gid += stride) {
        int row = (int)(gid >> 7);
        int c   = (int)(gid & 127);
        int b   = row >> 13;
        int p   = row & (MAXLEN_ - 1);
        const int* cm = cum + b * T_;
        int mel = cm[T_ - 1];
        f4 v = (f4){0.f, 0.f, 0.f, 0.f};
        if (p < mel) {
            int lo = 0, hi = T_;
            #pragma unroll
            for (int it = 0; it < 10; ++it) {
                int mid = (lo + hi) >> 1;
                if (cm[mid] <= p) lo = mid + 1; else hi = mid;
            }
            v = x[(((long long)(b * T_ + lo)) << 7) | c];
        }
        out[gid] = v;
    }
}

extern "C" void kernel_launch(void* const* d_in, const int* in_sizes, int n_in,
                              void* d_out, int out_size, void* d_ws, size_t ws_size,
                              hipStream_t stream) {
    const float* x   = (const float*)d_in[0];
    const int*   dur = (const int*)d_in[1];   // harness converts integers to int32
    // d_in[2] = max_len scalar (8192) -- compile-time constant here.

    float* out     = (float*)d_out;
    float* mel_out = out + (size_t)B_ * MAXLEN_ * D_;   // output 1 tail

    const size_t need_idx = (size_t)B_ * MAXLEN_ * sizeof(int);   // 1 MB

    if (ws_size >= need_idx) {
        int* idx = (int*)d_ws;
        lr_scan_scatter_kernel<<<B_, T_, 0, stream>>>(dur, idx, mel_out);
        // 262144 output rows / 8 rows per block = 32768 blocks (mult of 8)
        lr_gather_kernel<<<(B_ * MAXLEN_) / 8, 256, 0, stream>>>(
            (const f4*)x, idx, (f4*)out);
    } else {
        int* cum = (int*)d_ws;                            // 128 KB
        lr_cumsum_kernel<<<B_, T_, 0, stream>>>(dur, cum, mel_out);
        lr_gather_fused_kernel<<<4096, 256, 0, stream>>>((const f4*)x, cum,
                                                         (f4*)out);
    }
}